// Round 1
// baseline (178.528 us; speedup 1.0000x reference)
//
#include <hip/hip_runtime.h>

// LDPC min-sum layer, fused per-batch-row kernel.
// B=1024, N=4096, E=16384, colW=4, rowW-1=7.
#define BB   1024
#define NN   4096
#define EE   16384
#define COLW 4
#define ROWW1 7
#define TPB  1024

__global__ __launch_bounds__(TPB) void msl_fused_kernel(
    const float* __restrict__ channelLLR,   // [B,N]
    const float* __restrict__ e2oLLR,       // [B,E]
    const int*   __restrict__ edgeToVar,    // [B,N,4]
    const float* __restrict__ edgeToVarMask,// [B,N,4]
    const int*   __restrict__ oddToEven,    // [B,E]
    const int*   __restrict__ edgeToChk,    // [B,E,7]
    const float* __restrict__ alpha,        // [1]
    float*       __restrict__ out,          // [B,N]
    float*       __restrict__ e2o_out)      // [B,E]
{
    __shared__ __align__(16) float llr_lds[NN];    // 16 KB
    __shared__ __align__(16) float edge_lds[EE];   // 64 KB
    const int b   = blockIdx.x;
    const int tid = threadIdx.x;
    const float alph = alpha[0];

    // ---- Phase 0: stage e2oLLR row into LDS (coalesced float4) ----
    {
        const float4* __restrict__ src = reinterpret_cast<const float4*>(e2oLLR + (size_t)b * EE);
        float4* dst = reinterpret_cast<float4*>(edge_lds);
        #pragma unroll
        for (int k = 0; k < EE / 4 / TPB; ++k) {     // 4 iters
            int i = tid + k * TPB;
            dst[i] = src[i];
        }
    }
    __syncthreads();

    // ---- Phase 1: llr[n] = ch[n] + sum_c e2o[idx_c]*mask_c ----
    float chreg[NN / TPB];
    int4  idxreg[NN / TPB];
    float4 mreg[NN / TPB];
    {
        const int4*   __restrict__ ev4 = reinterpret_cast<const int4*>(edgeToVar + (size_t)b * NN * COLW);
        const float4* __restrict__ mk4 = reinterpret_cast<const float4*>(edgeToVarMask + (size_t)b * NN * COLW);
        const float*  __restrict__ chrow = channelLLR + (size_t)b * NN;
        #pragma unroll
        for (int k = 0; k < NN / TPB; ++k) {         // 4 iters
            int n = tid + k * TPB;
            float ch = chrow[n];
            int4  idx = ev4[n];
            float4 m  = mk4[n];
            float acc = ch;
            acc += edge_lds[idx.x] * m.x;
            acc += edge_lds[idx.y] * m.y;
            acc += edge_lds[idx.z] * m.z;
            acc += edge_lds[idx.w] * m.w;
            llr_lds[n] = acc;
            chreg[k] = ch; idxreg[k] = idx; mreg[k] = m;
        }
    }
    __syncthreads();

    // ---- Phase 2: vllr[e] = llr[o2e[e]] - e2oLLR[e], in place ----
    {
        const int* __restrict__ o2erow = oddToEven + (size_t)b * EE;
        #pragma unroll
        for (int k = 0; k < EE / TPB; ++k) {         // 16 iters
            int e = tid + k * TPB;
            int o = o2erow[e];
            float v = llr_lds[o] - edge_lds[e];
            edge_lds[e] = v;                          // element-wise ownership: safe
        }
    }
    __syncthreads();

    // ---- Phase 3: min-sum over 7 peer edges (LDS gathers) ----
    float e2oreg[EE / TPB];
    {
        const int* __restrict__ ecrow = edgeToChk + (size_t)b * EE * ROWW1;
        float* __restrict__ e2orow = e2o_out + (size_t)b * EE;
        #pragma unroll
        for (int k = 0; k < EE / TPB; ++k) {         // 16 iters
            int e = tid + k * TPB;
            const int* __restrict__ p = ecrow + (size_t)e * ROWW1;
            float mn = 3.0e38f;
            unsigned sgn = 0u;
            #pragma unroll
            for (int j = 0; j < ROWW1; ++j) {
                float v = edge_lds[p[j]];
                sgn ^= __float_as_uint(v);
                mn = fminf(mn, fabsf(v));
            }
            float val = mn * alph;
            float r = __uint_as_float(__float_as_uint(val) ^ (sgn & 0x80000000u));
            e2oreg[k] = r;
            e2orow[e] = r;
        }
    }
    __syncthreads();

    // ---- stash e2o into LDS for phase 4 gathers ----
    #pragma unroll
    for (int k = 0; k < EE / TPB; ++k) {
        edge_lds[tid + k * TPB] = e2oreg[k];
    }
    __syncthreads();

    // ---- Phase 4: out[n] = ch[n] + sum_c e2o[idx_c]*mask_c ----
    {
        float* __restrict__ outrow = out + (size_t)b * NN;
        #pragma unroll
        for (int k = 0; k < NN / TPB; ++k) {         // 4 iters
            int n = tid + k * TPB;
            int4  idx = idxreg[k];
            float4 m  = mreg[k];
            float acc = chreg[k];
            acc += edge_lds[idx.x] * m.x;
            acc += edge_lds[idx.y] * m.y;
            acc += edge_lds[idx.z] * m.z;
            acc += edge_lds[idx.w] * m.w;
            outrow[n] = acc;
        }
    }
}

extern "C" void kernel_launch(void* const* d_in, const int* in_sizes, int n_in,
                              void* d_out, int out_size, void* d_ws, size_t ws_size,
                              hipStream_t stream) {
    const float* channelLLR    = (const float*)d_in[0];
    const float* e2oLLR        = (const float*)d_in[1];
    // d_in[2] = maxColWeight (int scalar, ==4, baked in)
    const int*   edgeToVar     = (const int*)d_in[3];
    const float* edgeToVarMask = (const float*)d_in[4];
    const int*   oddToEven     = (const int*)d_in[5];
    const int*   edgeToChk     = (const int*)d_in[6];
    // d_in[7] = rowWeight (int scalar, ==8, baked in)
    const float* alpha         = (const float*)d_in[8];

    float* out     = (float*)d_out;            // [B,N]
    float* e2o_out = (float*)d_out + (size_t)BB * NN;  // [B,E]

    msl_fused_kernel<<<BB, TPB, 0, stream>>>(
        channelLLR, e2oLLR, edgeToVar, edgeToVarMask,
        oddToEven, edgeToChk, alpha, out, e2o_out);
}

// Round 2
// 178.347 us; speedup vs baseline: 1.0010x; 1.0010x over previous
//
#include <hip/hip_runtime.h>

// LDPC min-sum layer, fused per-batch-row kernel.
// B=1024, N=4096, E=16384, colW=4, rowW-1=7.
// 512 threads/block + 80KB LDS -> 2 blocks/CU co-resident (cross-block
// HBM/LDS overlap). __launch_bounds__(512,4) caps VGPR at 128.
#define BB   1024
#define NN   4096
#define EE   16384
#define COLW 4
#define ROWW1 7
#define TPB  512

__global__ __launch_bounds__(TPB, 4) void msl_fused_kernel(
    const float* __restrict__ channelLLR,   // [B,N]
    const float* __restrict__ e2oLLR,       // [B,E]
    const int*   __restrict__ edgeToVar,    // [B,N,4]
    const float* __restrict__ edgeToVarMask,// [B,N,4]
    const int*   __restrict__ oddToEven,    // [B,E]
    const int*   __restrict__ edgeToChk,    // [B,E,7]
    const float* __restrict__ alpha,        // [1]
    float*       __restrict__ out,          // [B,N]
    float*       __restrict__ e2o_out)      // [B,E]
{
    __shared__ __align__(16) float llr_lds[NN];    // 16 KB
    __shared__ __align__(16) float edge_lds[EE];   // 64 KB
    const int b   = blockIdx.x;
    const int tid = threadIdx.x;
    const float alph = alpha[0];

    // ---- Phase 0: stage e2oLLR row into LDS (coalesced float4) ----
    {
        const float4* __restrict__ src = reinterpret_cast<const float4*>(e2oLLR + (size_t)b * EE);
        float4* dst = reinterpret_cast<float4*>(edge_lds);
        #pragma unroll
        for (int k = 0; k < EE / 4 / TPB; ++k) {     // 8 iters
            int i = tid + k * TPB;
            dst[i] = src[i];
        }
    }
    __syncthreads();

    // ---- Phase 1: llr[n] = ch[n] + sum_c e2o[idx_c]*mask_c ----
    int4   idxreg[NN / TPB];   // 8 x int4  = 32 VGPR (reused in phase 4)
    float4 mreg[NN / TPB];     // 8 x float4= 32 VGPR (reused in phase 4)
    {
        const int4*   __restrict__ ev4 = reinterpret_cast<const int4*>(edgeToVar + (size_t)b * NN * COLW);
        const float4* __restrict__ mk4 = reinterpret_cast<const float4*>(edgeToVarMask + (size_t)b * NN * COLW);
        const float*  __restrict__ chrow = channelLLR + (size_t)b * NN;
        #pragma unroll
        for (int k = 0; k < NN / TPB; ++k) {         // 8 iters
            int n = tid + k * TPB;
            int4  idx = ev4[n];
            float4 m  = mk4[n];
            float acc = chrow[n];
            acc += edge_lds[idx.x] * m.x;
            acc += edge_lds[idx.y] * m.y;
            acc += edge_lds[idx.z] * m.z;
            acc += edge_lds[idx.w] * m.w;
            llr_lds[n] = acc;
            idxreg[k] = idx; mreg[k] = m;
        }
    }
    __syncthreads();

    // ---- Phase 2: vllr[e] = llr[o2e[e]] - e2oLLR[e], in place ----
    {
        const int* __restrict__ o2erow = oddToEven + (size_t)b * EE;
        #pragma unroll 8
        for (int k = 0; k < EE / TPB; ++k) {         // 32 iters
            int e = tid + k * TPB;
            int o = o2erow[e];
            float v = llr_lds[o] - edge_lds[e];
            edge_lds[e] = v;                          // element-wise ownership: safe
        }
    }
    __syncthreads();

    // ---- Phase 3: min-sum over 7 peer edges (LDS gathers) ----
    float e2oreg[EE / TPB];    // 32 VGPR
    {
        const int* __restrict__ ecrow = edgeToChk + (size_t)b * EE * ROWW1;
        float* __restrict__ e2orow = e2o_out + (size_t)b * EE;
        #pragma unroll
        for (int k = 0; k < EE / TPB; ++k) {         // 32 iters (full unroll: e2oreg static idx)
            int e = tid + k * TPB;
            const int* __restrict__ p = ecrow + (size_t)e * ROWW1;
            float mn = 3.0e38f;
            unsigned sgn = 0u;
            #pragma unroll
            for (int j = 0; j < ROWW1; ++j) {
                float v = edge_lds[p[j]];
                sgn ^= __float_as_uint(v);
                mn = fminf(mn, fabsf(v));
            }
            float val = mn * alph;
            float r = __uint_as_float(__float_as_uint(val) ^ (sgn & 0x80000000u));
            e2oreg[k] = r;
            e2orow[e] = r;
        }
    }
    __syncthreads();

    // ---- stash e2o into LDS for phase 4 gathers ----
    #pragma unroll
    for (int k = 0; k < EE / TPB; ++k) {
        edge_lds[tid + k * TPB] = e2oreg[k];
    }
    __syncthreads();

    // ---- Phase 4: out[n] = ch[n] + sum_c e2o[idx_c]*mask_c ----
    {
        float* __restrict__ outrow = out + (size_t)b * NN;
        const float* __restrict__ chrow = channelLLR + (size_t)b * NN;
        #pragma unroll
        for (int k = 0; k < NN / TPB; ++k) {         // 8 iters
            int n = tid + k * TPB;
            int4  idx = idxreg[k];
            float4 m  = mreg[k];
            float acc = chrow[n];
            acc += edge_lds[idx.x] * m.x;
            acc += edge_lds[idx.y] * m.y;
            acc += edge_lds[idx.z] * m.z;
            acc += edge_lds[idx.w] * m.w;
            outrow[n] = acc;
        }
    }
}

extern "C" void kernel_launch(void* const* d_in, const int* in_sizes, int n_in,
                              void* d_out, int out_size, void* d_ws, size_t ws_size,
                              hipStream_t stream) {
    const float* channelLLR    = (const float*)d_in[0];
    const float* e2oLLR        = (const float*)d_in[1];
    // d_in[2] = maxColWeight (int scalar, ==4, baked in)
    const int*   edgeToVar     = (const int*)d_in[3];
    const float* edgeToVarMask = (const float*)d_in[4];
    const int*   oddToEven     = (const int*)d_in[5];
    const int*   edgeToChk     = (const int*)d_in[6];
    // d_in[7] = rowWeight (int scalar, ==8, baked in)
    const float* alpha         = (const float*)d_in[8];

    float* out     = (float*)d_out;            // [B,N]
    float* e2o_out = (float*)d_out + (size_t)BB * NN;  // [B,E]

    msl_fused_kernel<<<BB, TPB, 0, stream>>>(
        channelLLR, e2oLLR, edgeToVar, edgeToVarMask,
        oddToEven, edgeToChk, alpha, out, e2o_out);
}

// Round 4
// 166.667 us; speedup vs baseline: 1.0712x; 1.0701x over previous
//
#include <hip/hip_runtime.h>

// LDPC min-sum layer, fused per-batch-row kernel.
// B=1024, N=4096, E=16384, colW=4, rowW-1=7.
// Phase 3: lane-transposed coalesced index loads (7x fewer cache-line
// touches) + wave-private double-buffered LDS redistribution with an
// explicit wave-level lgkmcnt fence (no block barrier -> waves stay async).
#define BB   1024
#define NN   4096
#define EE   16384
#define COLW 4
#define ROWW1 7
#define TPB  1024
#define NWAVE (TPB / 64)          // 16
#define GRP_DW (64 * ROWW1)       // 448 dwords per 64-edge group
#define SCR_DW (NWAVE * GRP_DW)   // 7168 dwords per scratch buffer

__global__ __launch_bounds__(TPB) void msl_fused_kernel(
    const float* __restrict__ channelLLR,   // [B,N]
    const float* __restrict__ e2oLLR,       // [B,E]
    const int*   __restrict__ edgeToVar,    // [B,N,4]
    const float* __restrict__ edgeToVarMask,// [B,N,4]
    const int*   __restrict__ oddToEven,    // [B,E]
    const int*   __restrict__ edgeToChk,    // [B,E,7]
    const float* __restrict__ alpha,        // [1]
    float*       __restrict__ out,          // [B,N]
    float*       __restrict__ e2o_out)      // [B,E]
{
    // scr_lds: first NN floats serve as llr in phases 1-2; phase 3 uses the
    // whole region as 2x double-buffered per-wave redistribution scratch.
    __shared__ __align__(16) float scr_lds[2 * SCR_DW];      // 56 KB
    __shared__ __align__(16) float edge_lds[EE];             // 64 KB
    const int b    = blockIdx.x;
    const int tid  = threadIdx.x;
    const int wave = tid >> 6;
    const int lane = tid & 63;
    const float alph = alpha[0];

    // ---- Phase 0: stage e2oLLR row into LDS (coalesced float4) ----
    {
        const float4* __restrict__ src = reinterpret_cast<const float4*>(e2oLLR + (size_t)b * EE);
        float4* dst = reinterpret_cast<float4*>(edge_lds);
        #pragma unroll
        for (int k = 0; k < EE / 4 / TPB; ++k) {     // 4 iters
            int i = tid + k * TPB;
            dst[i] = src[i];
        }
    }
    __syncthreads();

    // ---- Phase 1: llr[n] = ch[n] + sum_c e2o[idx_c]*mask_c ----
    int4   idxreg[NN / TPB];   // 4 x int4   = 16 VGPR (reused in phase 4)
    float4 mreg[NN / TPB];     // 4 x float4 = 16 VGPR (reused in phase 4)
    {
        const int4*   __restrict__ ev4 = reinterpret_cast<const int4*>(edgeToVar + (size_t)b * NN * COLW);
        const float4* __restrict__ mk4 = reinterpret_cast<const float4*>(edgeToVarMask + (size_t)b * NN * COLW);
        const float*  __restrict__ chrow = channelLLR + (size_t)b * NN;
        #pragma unroll
        for (int k = 0; k < NN / TPB; ++k) {         // 4 iters
            int n = tid + k * TPB;
            int4  idx = ev4[n];
            float4 m  = mk4[n];
            float acc = chrow[n];
            acc += edge_lds[idx.x] * m.x;
            acc += edge_lds[idx.y] * m.y;
            acc += edge_lds[idx.z] * m.z;
            acc += edge_lds[idx.w] * m.w;
            scr_lds[n] = acc;                         // llr lives in scratch buf 0
            idxreg[k] = idx; mreg[k] = m;
        }
    }
    __syncthreads();

    // ---- Phase 2: vllr[e] = llr[o2e[e]] - e2oLLR[e], in place ----
    {
        const int* __restrict__ o2erow = oddToEven + (size_t)b * EE;
        #pragma unroll 8
        for (int k = 0; k < EE / TPB; ++k) {         // 16 iters
            int e = tid + k * TPB;
            int o = o2erow[e];
            float v = scr_lds[o] - edge_lds[e];
            edge_lds[e] = v;                          // element-wise ownership: safe
        }
    }
    __syncthreads();
    // llr region dead from here on -> scr_lds is pure phase-3 scratch.

    // ---- Phase 3: min-sum over 7 peer edges ----
    // Per wave, per iteration: 64 edges (group g). Coalesced transposed load
    // of the group's 448 indices (7 x 256B-contiguous dword loads), gather
    // vllr immediately (lane order irrelevant), scatter into wave-private
    // scratch, wave-level fence, read back edge-major, reduce in registers.
    float e2oreg[EE / TPB];    // 16 VGPR
    {
        const int* __restrict__ ecrow = edgeToChk + (size_t)b * (size_t)EE * ROWW1;
        float* __restrict__ e2orow = e2o_out + (size_t)b * EE;
        int idx[ROWW1];
        {   // prologue: indices for it=0
            const int* __restrict__ p = ecrow + (size_t)wave * GRP_DW + lane;
            #pragma unroll
            for (int j = 0; j < ROWW1; ++j) idx[j] = p[64 * j];
        }
        #pragma unroll
        for (int it = 0; it < EE / TPB; ++it) {      // 16 iters
            const int g = it * NWAVE + wave;
            float* __restrict__ scratch = scr_lds + (it & 1) * SCR_DW + wave * GRP_DW;
            // gather vllr + scatter to scratch (write bank stride 64 -> 2-way, free)
            #pragma unroll
            for (int j = 0; j < ROWW1; ++j) scratch[lane + 64 * j] = edge_lds[idx[j]];
            // prefetch next group's indices; stays in flight across the
            // lgkmcnt-only fence below (fence doesn't drain vmcnt).
            if (it + 1 < EE / TPB) {
                const int* __restrict__ p = ecrow + (size_t)(g + NWAVE) * GRP_DW + lane;
                #pragma unroll
                for (int j = 0; j < ROWW1; ++j) idx[j] = p[64 * j];
            }
            // wave-level ordering: ds_writes committed before readback issues.
            __builtin_amdgcn_wave_barrier();
            asm volatile("s_waitcnt lgkmcnt(0)" ::: "memory");
            __builtin_amdgcn_wave_barrier();
            // read back edge-major (stride 7, coprime 32 -> 2-way, free)
            float mn = 3.0e38f;
            unsigned sgn = 0u;
            const float* __restrict__ sb = scratch + lane * ROWW1;
            #pragma unroll
            for (int j = 0; j < ROWW1; ++j) {
                float u = sb[j];
                sgn ^= __float_as_uint(u);
                mn = fminf(mn, fabsf(u));
            }
            float val = mn * alph;
            float r = __uint_as_float(__float_as_uint(val) ^ (sgn & 0x80000000u));
            e2oreg[it] = r;                           // edge 64g+lane == it*TPB+tid
            e2orow[64 * g + lane] = r;                // coalesced store
        }
    }
    __syncthreads();

    // ---- stash e2o into LDS for phase 4 gathers ----
    #pragma unroll
    for (int k = 0; k < EE / TPB; ++k) {
        edge_lds[tid + k * TPB] = e2oreg[k];          // same edge mapping as above
    }
    __syncthreads();

    // ---- Phase 4: out[n] = ch[n] + sum_c e2o[idx_c]*mask_c ----
    {
        float* __restrict__ outrow = out + (size_t)b * NN;
        const float* __restrict__ chrow = channelLLR + (size_t)b * NN;
        #pragma unroll
        for (int k = 0; k < NN / TPB; ++k) {         // 4 iters
            int n = tid + k * TPB;
            int4  idx = idxreg[k];
            float4 m  = mreg[k];
            float acc = chrow[n];
            acc += edge_lds[idx.x] * m.x;
            acc += edge_lds[idx.y] * m.y;
            acc += edge_lds[idx.z] * m.z;
            acc += edge_lds[idx.w] * m.w;
            outrow[n] = acc;
        }
    }
}

extern "C" void kernel_launch(void* const* d_in, const int* in_sizes, int n_in,
                              void* d_out, int out_size, void* d_ws, size_t ws_size,
                              hipStream_t stream) {
    const float* channelLLR    = (const float*)d_in[0];
    const float* e2oLLR        = (const float*)d_in[1];
    // d_in[2] = maxColWeight (int scalar, ==4, baked in)
    const int*   edgeToVar     = (const int*)d_in[3];
    const float* edgeToVarMask = (const float*)d_in[4];
    const int*   oddToEven     = (const int*)d_in[5];
    const int*   edgeToChk     = (const int*)d_in[6];
    // d_in[7] = rowWeight (int scalar, ==8, baked in)
    const float* alpha         = (const float*)d_in[8];

    float* out     = (float*)d_out;            // [B,N]
    float* e2o_out = (float*)d_out + (size_t)BB * NN;  // [B,E]

    msl_fused_kernel<<<BB, TPB, 0, stream>>>(
        channelLLR, e2oLLR, edgeToVar, edgeToVarMask,
        oddToEven, edgeToChk, alpha, out, e2o_out);
}